// Round 3
// baseline (296.919 us; speedup 1.0000x reference)
//
#include <hip/hip_runtime.h>
#include <hip/hip_bf16.h>

#define BATCH 16
#define SEQ   2048
#define DIM   128
#define L2E   1.4426950408889634f
#define THR   8.0f
#define MSENT -100

typedef __attribute__((ext_vector_type(8))) short bf16x8;
typedef __attribute__((ext_vector_type(4))) short bf16x4;
typedef __attribute__((ext_vector_type(4))) float f32x4;
typedef __attribute__((ext_vector_type(4))) int   i32x4;
typedef __attribute__((ext_vector_type(2))) unsigned u32x2;
typedef __attribute__((ext_vector_type(4))) unsigned u32x4;

__device__ __forceinline__ unsigned short f2bf(float f) {
  union { float f; unsigned u; } v; v.f = f;
  return (unsigned short)((v.u + 0x7FFFu + ((v.u >> 16) & 1u)) >> 16);  // RTNE
}
__device__ __forceinline__ unsigned packbf(float a, float b) {
  return ((unsigned)f2bf(b) << 16) | (unsigned)f2bf(a);
}

// ---------------- Pass 1a: K f32 -> bf16 (same layout) ----------------
__global__ __launch_bounds__(256) void cvt_k(const float* __restrict__ K,
                                             short* __restrict__ Kb) {
  const size_t i = ((size_t)blockIdx.x * 256 + threadIdx.x) * 8;
  f32x4 a = __builtin_nontemporal_load((const f32x4*)(K + i));
  f32x4 b = __builtin_nontemporal_load((const f32x4*)(K + i + 4));
  u32x4 o = { packbf(a[0], a[1]), packbf(a[2], a[3]),
              packbf(b[0], b[1]), packbf(b[2], b[3]) };
  *(u32x4*)(Kb + i) = o;
}

// ---------------- Pass 1b: V f32 [b][s][d] -> bf16 Vt [b][d][s] ----------------
__global__ __launch_bounds__(256) void cvt_vt(const float* __restrict__ V,
                                              short* __restrict__ Vt) {
  __shared__ unsigned t32[64][65];   // u32 = packed bf16 pair (d even, d odd)
  const int tid = threadIdx.x;
  const int b  = blockIdx.x >> 5;
  const int s0 = (blockIdx.x & 31) * 64;
  #pragma unroll
  for (int it = 0; it < 8; ++it) {
    const int idx = tid + it * 256;
    const int r = idx >> 5, c4 = idx & 31;
    f32x4 x = __builtin_nontemporal_load(
        (const f32x4*)(V + ((size_t)b * SEQ + s0 + r) * DIM + c4 * 4));
    t32[r][c4 * 2]     = packbf(x[0], x[1]);
    t32[r][c4 * 2 + 1] = packbf(x[2], x[3]);
  }
  __syncthreads();
  const int d = tid >> 1, sh = tid & 1;
  unsigned short outv[32];
  #pragma unroll
  for (int j = 0; j < 32; ++j) {
    const unsigned u = t32[sh * 32 + j][d >> 1];
    outv[j] = (d & 1) ? (unsigned short)(u >> 16) : (unsigned short)(u & 0xffff);
  }
  short* op = Vt + ((size_t)b * DIM + d) * SEQ + s0 + sh * 32;
  #pragma unroll
  for (int q = 0; q < 4; ++q) {
    bf16x8 y;
    #pragma unroll
    for (int j = 0; j < 8; ++j) y[j] = (short)outv[q * 8 + j];
    *(bf16x8*)(op + q * 8) = y;
  }
}

// ---------------- Pass 2: kv-split flash attention ----------------
// Block: 16 q-rows, 4 waves; wave w covers kv in [w*512, (w+1)*512).
// Swapped QK^T (C rows = kv, cols = q) so softmax state is lane-local (q = lr).
__global__ __launch_bounds__(256, 3) void attn_split(
    const float* __restrict__ Qg, const short* __restrict__ Kbf,
    const short* __restrict__ Vt, const int* __restrict__ Mg,
    float* __restrict__ Og) {
  __shared__ unsigned pa_lds[4][16][40];   // per-wave P row buffer (kv dword-pairs)
  __shared__ float accw[4][16][132];       // per-wave partial O
  __shared__ float MW[4][16], LW[4][16];

  const int tid = threadIdx.x;
  const int w = tid >> 6, l = tid & 63, g = l >> 4, lr = l & 15;
  const int bid = blockIdx.x;
  const int swz = (bid & 7) * 256 + (bid >> 3);   // XCD-chunked (2048 % 8 == 0)
  const int b   = swz >> 7;
  const int q0  = (swz & 127) * 16;
  const int kvw = w * (SEQ / 4);

  const float scale = 0.08838834764831845f;  // 1/sqrt(128)

  // Q fragments (B-operand role; per-lane data identical to A-layout): q = lr
  bf16x8 qa[4];
  {
    const float* qbase = Qg + ((size_t)b * SEQ + q0 + lr) * DIM + g * 8;
    #pragma unroll
    for (int kk = 0; kk < 4; ++kk) {
      f32x4 x0 = *(const f32x4*)(qbase + kk * 32);
      f32x4 x1 = *(const f32x4*)(qbase + kk * 32 + 4);
      bf16x8 f;
      #pragma unroll
      for (int j = 0; j < 4; ++j) {
        f[j]     = (short)f2bf(x0[j] * scale);
        f[j + 4] = (short)f2bf(x1[j] * scale);
      }
      qa[kk] = f;
    }
  }

  const short* Kb = Kbf + (size_t)b * SEQ * DIM;
  const short* Vb = Vt  + (size_t)b * DIM * SEQ;
  const int*   Mr = Mg + (size_t)b * SEQ * SEQ + (size_t)(q0 + lr) * SEQ;

  f32x4 acc[8];
  #pragma unroll
  for (int t = 0; t < 8; ++t) acc[t] = (f32x4){0.f, 0.f, 0.f, 0.f};
  float mrow = -1e30f, lsum = 0.f;

  i32x4 mreg[4];
  #pragma unroll
  for (int sub = 0; sub < 4; ++sub)
    mreg[sub] = __builtin_nontemporal_load(
        (const i32x4*)(Mr + kvw + 16 * sub + 4 * g));

  for (int t = 0; t < 8; ++t) {
    const int kv0 = kvw + t * 64;

    // ---- QK^T (swapped): s[sub] = S^T tile rows kv=16sub+4g+i, col q=lr
    f32x4 s[4];
    #pragma unroll
    for (int sub = 0; sub < 4; ++sub) s[sub] = (f32x4){0.f, 0.f, 0.f, 0.f};
    #pragma unroll
    for (int kk = 0; kk < 4; ++kk) {
      bf16x8 kf0 = *(const bf16x8*)(Kb + (size_t)(kv0      + lr) * DIM + kk * 32 + g * 8);
      bf16x8 kf1 = *(const bf16x8*)(Kb + (size_t)(kv0 + 16 + lr) * DIM + kk * 32 + g * 8);
      bf16x8 kf2 = *(const bf16x8*)(Kb + (size_t)(kv0 + 32 + lr) * DIM + kk * 32 + g * 8);
      bf16x8 kf3 = *(const bf16x8*)(Kb + (size_t)(kv0 + 48 + lr) * DIM + kk * 32 + g * 8);
      s[0] = __builtin_amdgcn_mfma_f32_16x16x32_bf16(kf0, qa[kk], s[0], 0, 0, 0);
      s[1] = __builtin_amdgcn_mfma_f32_16x16x32_bf16(kf1, qa[kk], s[1], 0, 0, 0);
      s[2] = __builtin_amdgcn_mfma_f32_16x16x32_bf16(kf2, qa[kk], s[2], 0, 0, 0);
      s[3] = __builtin_amdgcn_mfma_f32_16x16x32_bf16(kf3, qa[kk], s[3], 0, 0, 0);
    }

    // ---- V prefetch for PV steps 0,1 (latency hides under softmax)
    bf16x8 vf[2][2];
    #pragma unroll
    for (int p = 0; p < 2; ++p)
      #pragma unroll
      for (int kk2 = 0; kk2 < 2; ++kk2)
        vf[p][kk2] = *(const bf16x8*)(Vb + (size_t)(16 * p + lr) * SEQ +
                                      kv0 + kk2 * 32 + g * 8);

    // ---- mask apply (kv = 16sub + 4g + i, q = lr)
    #pragma unroll
    for (int sub = 0; sub < 4; ++sub) {
      #pragma unroll
      for (int i = 0; i < 4; ++i)
        if (mreg[sub][i] == MSENT) s[sub][i] = -1e30f;
    }
    if (t < 7) {
      #pragma unroll
      for (int sub = 0; sub < 4; ++sub)
        mreg[sub] = __builtin_nontemporal_load(
            (const i32x4*)(Mr + kv0 + 64 + 16 * sub + 4 * g));
    }

    // ---- online softmax, lane-local row q=lr; defer-max (T13)
    float tm = s[0][0];
    #pragma unroll
    for (int sub = 0; sub < 4; ++sub)
      #pragma unroll
      for (int i = 0; i < 4; ++i) tm = fmaxf(tm, s[sub][i]);
    tm = fmaxf(tm, __shfl_xor(tm, 16));
    tm = fmaxf(tm, __shfl_xor(tm, 32));
    if (__any(tm > mrow + THR)) {
      const float mnew = fmaxf(mrow, tm);
      const float al = __builtin_amdgcn_exp2f((mrow - mnew) * L2E);
      mrow = mnew; lsum *= al;
      float av[4];
      #pragma unroll
      for (int i = 0; i < 4; ++i) av[i] = __shfl(al, g * 16 + 4 * g + i);
      #pragma unroll
      for (int t8 = 0; t8 < 8; ++t8)
        #pragma unroll
        for (int i = 0; i < 4; ++i) acc[t8][i] *= av[i];
    }

    // ---- P = exp2((s-m)*L2E), pack to bf16 pairs, stage via tiny LDS
    unsigned pk[4][2];
    #pragma unroll
    for (int sub = 0; sub < 4; ++sub) {
      const float p0 = __builtin_amdgcn_exp2f((s[sub][0] - mrow) * L2E);
      const float p1 = __builtin_amdgcn_exp2f((s[sub][1] - mrow) * L2E);
      const float p2 = __builtin_amdgcn_exp2f((s[sub][2] - mrow) * L2E);
      const float p3 = __builtin_amdgcn_exp2f((s[sub][3] - mrow) * L2E);
      lsum += (p0 + p1) + (p2 + p3);
      pk[sub][0] = packbf(p0, p1);
      pk[sub][1] = packbf(p2, p3);
    }
    #pragma unroll
    for (int sub = 0; sub < 4; ++sub)
      *(u32x2*)&pa_lds[w][lr][8 * sub + 2 * g] = (u32x2){pk[sub][0], pk[sub][1]};
    // A-fragments for PV: P[q=lr][kv = kk*32 + 8g + j]
    bf16x8 pa0 = *(const bf16x8*)&pa_lds[w][lr][4 * g];
    bf16x8 pa1 = *(const bf16x8*)&pa_lds[w][lr][16 + 4 * g];

    // ---- PV with depth-2 V prefetch
    #pragma unroll
    for (int t8 = 0; t8 < 8; ++t8) {
      const int cur = t8 & 1;
      acc[t8] = __builtin_amdgcn_mfma_f32_16x16x32_bf16(pa0, vf[cur][0], acc[t8], 0, 0, 0);
      acc[t8] = __builtin_amdgcn_mfma_f32_16x16x32_bf16(pa1, vf[cur][1], acc[t8], 0, 0, 0);
      if (t8 < 6) {
        #pragma unroll
        for (int kk2 = 0; kk2 < 2; ++kk2)
          vf[cur][kk2] = *(const bf16x8*)(Vb + (size_t)(16 * (t8 + 2) + lr) * SEQ +
                                          kv0 + kk2 * 32 + g * 8);
      }
    }
  }

  // ---- epilogue: per-wave partials -> LDS, merge across 4 kv-slices
  lsum += __shfl_xor(lsum, 16);
  lsum += __shfl_xor(lsum, 32);
  if (l < 16) { MW[w][l] = mrow; LW[w][l] = lsum; }
  #pragma unroll
  for (int t8 = 0; t8 < 8; ++t8)
    #pragma unroll
    for (int i = 0; i < 4; ++i)
      accw[w][4 * g + i][16 * t8 + lr] = acc[t8][i];
  __syncthreads();

  const int r = tid >> 4, db = (tid & 15) * 8;
  const float m0 = MW[0][r], m1 = MW[1][r], m2 = MW[2][r], m3 = MW[3][r];
  const float M = fmaxf(fmaxf(m0, m1), fmaxf(m2, m3));
  const float sc0 = __builtin_amdgcn_exp2f((m0 - M) * L2E);
  const float sc1 = __builtin_amdgcn_exp2f((m1 - M) * L2E);
  const float sc2 = __builtin_amdgcn_exp2f((m2 - M) * L2E);
  const float sc3 = __builtin_amdgcn_exp2f((m3 - M) * L2E);
  const float L = sc0 * LW[0][r] + sc1 * LW[1][r] + sc2 * LW[2][r] + sc3 * LW[3][r];
  const float inv = 1.f / L;
  f32x4 oa = (f32x4){0.f, 0.f, 0.f, 0.f}, ob = (f32x4){0.f, 0.f, 0.f, 0.f};
  const float scv[4] = {sc0, sc1, sc2, sc3};
  #pragma unroll
  for (int w4 = 0; w4 < 4; ++w4) {
    f32x4 x0 = *(const f32x4*)&accw[w4][r][db];
    f32x4 x1 = *(const f32x4*)&accw[w4][r][db + 4];
    oa += scv[w4] * x0;
    ob += scv[w4] * x1;
  }
  oa *= inv; ob *= inv;
  float* op = Og + ((size_t)b * SEQ + q0 + r) * DIM + db;
  __builtin_nontemporal_store(oa, (f32x4*)op);
  __builtin_nontemporal_store(ob, (f32x4*)(op + 4));
}

// ---------------- Fallback (proven R2 kernel) if ws too small ----------------
#define QBLK  64
#define KVBLK 64
#define NT    (SEQ / KVBLK)
#define KPAD  136
#define VPAD  68
#define PPAD  72

__device__ __forceinline__ void issue_kv_fb(const float* __restrict__ Kb,
                                            const float* __restrict__ Vb,
                                            int k0, int tid,
                                            float4 (&kreg)[8], float (&vreg)[32]) {
  #pragma unroll
  for (int it = 0; it < 8; ++it) {
    const int idx = tid + it * 256;
    kreg[it] = *(const float4*)(Kb + (size_t)(k0 + (idx >> 5)) * DIM + (idx & 31) * 4);
  }
  const int d = tid & 127;
  #pragma unroll
  for (int st = 0; st < 8; ++st) {
    const int kv0 = ((tid >> 7) + 2 * st) * 4;
    #pragma unroll
    for (int j = 0; j < 4; ++j)
      vreg[st * 4 + j] = Vb[(size_t)(k0 + kv0 + j) * DIM + d];
  }
}
__device__ __forceinline__ void issue_m_fb(const int* const (&Mrow)[4], int k0,
                                           int (&mreg)[16]) {
  #pragma unroll
  for (int sub = 0; sub < 4; ++sub)
    #pragma unroll
    for (int i = 0; i < 4; ++i)
      mreg[sub * 4 + i] = Mrow[i][k0 + sub * 16];
}

__global__ __launch_bounds__(256, 2) void attn_fwd_fb(
    const float* __restrict__ Vg, const float* __restrict__ Kg,
    const float* __restrict__ Qg, const int* __restrict__ Mg,
    float* __restrict__ Og) {
  __shared__ short lds_k[KVBLK * KPAD];
  __shared__ short lds_vt[DIM * VPAD];
  __shared__ short lds_p[4][16 * PPAD];
  const int tid = threadIdx.x;
  const int w = tid >> 6, l = tid & 63, g = l >> 4, lr = l & 15;
  const int blk = blockIdx.x, b = blk >> 5, q0 = (blk & 31) * QBLK;
  const float scale = 0.08838834764831845f;
  bf16x8 qa[4];
  {
    const float* qbase = Qg + ((size_t)b * SEQ + (size_t)(q0 + w * 16 + lr)) * DIM + g * 8;
    #pragma unroll
    for (int kk = 0; kk < 4; ++kk) {
      const float4 x0 = *(const float4*)(qbase + kk * 32);
      const float4 x1 = *(const float4*)(qbase + kk * 32 + 4);
      bf16x8 f;
      f[0] = (short)f2bf(x0.x * scale); f[1] = (short)f2bf(x0.y * scale);
      f[2] = (short)f2bf(x0.z * scale); f[3] = (short)f2bf(x0.w * scale);
      f[4] = (short)f2bf(x1.x * scale); f[5] = (short)f2bf(x1.y * scale);
      f[6] = (short)f2bf(x1.z * scale); f[7] = (short)f2bf(x1.w * scale);
      qa[kk] = f;
    }
  }
  f32x4 acc[8];
  #pragma unroll
  for (int t = 0; t < 8; ++t) acc[t] = (f32x4){0.f, 0.f, 0.f, 0.f};
  float mrow[4] = {-1e30f, -1e30f, -1e30f, -1e30f};
  float lsum[4] = {0.f, 0.f, 0.f, 0.f};
  const float* Kb = Kg + (size_t)b * SEQ * DIM;
  const float* Vb = Vg + (size_t)b * SEQ * DIM;
  const int*   Mb = Mg + (size_t)b * SEQ * SEQ;
  const int* const Mrow[4] = {
    Mb + (size_t)(q0 + w * 16 + 4 * g + 0) * SEQ + lr,
    Mb + (size_t)(q0 + w * 16 + 4 * g + 1) * SEQ + lr,
    Mb + (size_t)(q0 + w * 16 + 4 * g + 2) * SEQ + lr,
    Mb + (size_t)(q0 + w * 16 + 4 * g + 3) * SEQ + lr };
  float4 kreg[8]; float vreg[32]; int mreg[16];
  issue_kv_fb(Kb, Vb, 0, tid, kreg, vreg);
  issue_m_fb(Mrow, 0, mreg);
  for (int t = 0; t < NT; ++t) {
    const int k0 = t * KVBLK;
    __syncthreads();
    #pragma unroll
    for (int it = 0; it < 8; ++it) {
      const int idx = tid + it * 256;
      const int row = idx >> 5, c4 = idx & 31;
      const float4 x = kreg[it];
      bf16x4 y;
      y[0] = (short)f2bf(x.x); y[1] = (short)f2bf(x.y);
      y[2] = (short)f2bf(x.z); y[3] = (short)f2bf(x.w);
      *(bf16x4*)&lds_k[row * KPAD + c4 * 4] = y;
    }
    {
      const int d = tid & 127;
      #pragma unroll
      for (int st = 0; st < 8; ++st) {
        const int kv0 = ((tid >> 7) + 2 * st) * 4;
        bf16x4 y;
        y[0] = (short)f2bf(vreg[st * 4 + 0]); y[1] = (short)f2bf(vreg[st * 4 + 1]);
        y[2] = (short)f2bf(vreg[st * 4 + 2]); y[3] = (short)f2bf(vreg[st * 4 + 3]);
        *(bf16x4*)&lds_vt[d * VPAD + kv0] = y;
      }
    }
    __syncthreads();
    if (t + 1 < NT) issue_kv_fb(Kb, Vb, k0 + KVBLK, tid, kreg, vreg);
    f32x4 s[4];
    #pragma unroll
    for (int sub = 0; sub < 4; ++sub) {
      f32x4 sv = (f32x4){0.f, 0.f, 0.f, 0.f};
      const int krow = sub * 16 + lr;
      #pragma unroll
      for (int kk = 0; kk < 4; ++kk) {
        bf16x8 kb = *(const bf16x8*)&lds_k[krow * KPAD + kk * 32 + g * 8];
        sv = __builtin_amdgcn_mfma_f32_16x16x32_bf16(qa[kk], kb, sv, 0, 0, 0);
      }
      s[sub] = sv;
    }
    #pragma unroll
    for (int sub = 0; sub < 4; ++sub)
      #pragma unroll
      for (int i = 0; i < 4; ++i)
        if (mreg[sub * 4 + i] == MSENT) s[sub][i] = -1e30f;
    if (t + 1 < NT) issue_m_fb(Mrow, k0 + KVBLK, mreg);
    float tmax[4]; bool chg = false;
    #pragma unroll
    for (int i = 0; i < 4; ++i) {
      float tm = fmaxf(fmaxf(s[0][i], s[1][i]), fmaxf(s[2][i], s[3][i]));
      #pragma unroll
      for (int dlt = 1; dlt < 16; dlt <<= 1)
        tm = fmaxf(tm, __shfl_xor(tm, dlt, 16));
      tmax[i] = tm;
      chg = chg || (tm > mrow[i] + THR);
    }
    if (__any(chg)) {
      #pragma unroll
      for (int i = 0; i < 4; ++i) {
        const float mnew = fmaxf(mrow[i], tmax[i]);
        const float alpha = __builtin_amdgcn_exp2f((mrow[i] - mnew) * L2E);
        mrow[i] = mnew; lsum[i] *= alpha;
        #pragma unroll
        for (int t8 = 0; t8 < 8; ++t8) acc[t8][i] *= alpha;
      }
    }
    #pragma unroll
    for (int sub = 0; sub < 4; ++sub)
      #pragma unroll
      for (int i = 0; i < 4; ++i) {
        const float p = __builtin_amdgcn_exp2f((s[sub][i] - mrow[i]) * L2E);
        lsum[i] += p;
        lds_p[w][(4 * g + i) * PPAD + sub * 16 + lr] = (short)f2bf(p);
      }
    bf16x8 pa[2];
    #pragma unroll
    for (int kk = 0; kk < 2; ++kk)
      pa[kk] = *(const bf16x8*)&lds_p[w][lr * PPAD + kk * 32 + g * 8];
    #pragma unroll
    for (int t8 = 0; t8 < 8; ++t8)
      #pragma unroll
      for (int kk = 0; kk < 2; ++kk) {
        const int voff = (16 * t8 + lr) * VPAD + kk * 32 + g * 8;
        bf16x4 v0 = *(const bf16x4*)&lds_vt[voff];
        bf16x4 v1 = *(const bf16x4*)&lds_vt[voff + 4];
        bf16x8 vb = __builtin_shufflevector(v0, v1, 0, 1, 2, 3, 4, 5, 6, 7);
        acc[t8] = __builtin_amdgcn_mfma_f32_16x16x32_bf16(pa[kk], vb, acc[t8], 0, 0, 0);
      }
  }
  float rden[4];
  #pragma unroll
  for (int i = 0; i < 4; ++i) {
    float sm = lsum[i];
    #pragma unroll
    for (int dlt = 1; dlt < 16; dlt <<= 1) sm += __shfl_xor(sm, dlt, 16);
    rden[i] = 1.f / sm;
  }
  float* ob = Og + ((size_t)b * SEQ + (size_t)(q0 + w * 16)) * DIM;
  #pragma unroll
  for (int t8 = 0; t8 < 8; ++t8)
    #pragma unroll
    for (int i = 0; i < 4; ++i)
      ob[(4 * g + i) * DIM + 16 * t8 + lr] = acc[t8][i] * rden[i];
}

extern "C" void kernel_launch(void* const* d_in, const int* in_sizes, int n_in,
                              void* d_out, int out_size, void* d_ws, size_t ws_size,
                              hipStream_t stream) {
  (void)in_sizes; (void)n_in; (void)out_size;
  const float* Vg = (const float*)d_in[0];
  const float* Kg = (const float*)d_in[1];
  const float* Qg = (const float*)d_in[2];
  const int*   Mg = (const int*)d_in[3];
  float* Og = (float*)d_out;

  const size_t need = (size_t)2 * BATCH * SEQ * DIM * sizeof(short);  // 16.8 MB
  if (ws_size >= need) {
    short* Kbf = (short*)d_ws;
    short* Vt  = Kbf + (size_t)BATCH * SEQ * DIM;
    cvt_k<<<dim3(BATCH * SEQ * DIM / (8 * 256)), 256, 0, stream>>>(Kg, Kbf);
    cvt_vt<<<dim3(BATCH * (SEQ / 64)), 256, 0, stream>>>(Vg, Vt);
    attn_split<<<dim3(BATCH * (SEQ / 16)), 256, 0, stream>>>(Qg, Kbf, Vt, Mg, Og);
  } else {
    attn_fwd_fb<<<dim3(BATCH * (SEQ / QBLK)), 256, 0, stream>>>(Vg, Kg, Qg, Mg, Og);
  }
}

// Round 4
// 134.857 us; speedup vs baseline: 2.2017x; 2.2017x over previous
//
#include <hip/hip_runtime.h>
#include <hip/hip_bf16.h>

#define BATCH 16
#define SEQ   2048
#define DIM   128
#define QBLK  64       // q rows per block (4 waves x 16)
#define KVBLK 64
#define NT    (SEQ / KVBLK)
#define KPAD  136      // lds_k row stride (elems)
#define VPAD  68       // lds_vt row stride (elems)
#define PPAD  72       // lds_p row stride (elems)
#define MPAD  68       // lds_m row stride (dwords), 272B = 16B-aligned
#define L2E   1.4426950408889634f
#define THR   8.0f     // defer-max rescale threshold (T13)
#define MSENT -100

typedef __attribute__((ext_vector_type(8))) short bf16x8;
typedef __attribute__((ext_vector_type(4))) short bf16x4;
typedef __attribute__((ext_vector_type(4))) float f32x4;
typedef __attribute__((ext_vector_type(4))) int   i32x4;

__device__ __forceinline__ short f2bf(float f) {
  union { float f; unsigned u; } v; v.f = f;
  unsigned r = (v.u + 0x7FFFu + ((v.u >> 16) & 1u)) >> 16;  // RTNE
  return (short)r;
}

// Issue next tile's K+V global loads into registers (T14 issue-early).
__device__ __forceinline__ void issue_kv(const float* __restrict__ Kb,
                                         const float* __restrict__ Vb,
                                         int k0, int tid,
                                         float4 (&kreg)[8], float (&vreg)[32]) {
  #pragma unroll
  for (int it = 0; it < 8; ++it) {
    const int idx = tid + it * 256;
    kreg[it] = *(const float4*)(Kb + (size_t)(k0 + (idx >> 5)) * DIM + (idx & 31) * 4);
  }
  const int d = tid & 127;
  #pragma unroll
  for (int st = 0; st < 8; ++st) {
    const int kv0 = ((tid >> 7) + 2 * st) * 4;
    #pragma unroll
    for (int j = 0; j < 4; ++j)
      vreg[st * 4 + j] = Vb[(size_t)(k0 + kv0 + j) * DIM + d];
  }
}

// Issue next tile's mask loads, coalesced i32x4 (4 instr, 256B-contig segs).
__device__ __forceinline__ void issue_m(const int* __restrict__ Mb,
                                        int q0, int k0, int tid,
                                        i32x4 (&mreg)[4]) {
  #pragma unroll
  for (int it = 0; it < 4; ++it) {
    const int idx = tid + it * 256;       // 0..1023
    const int row = idx >> 4;             // 0..63 (block-relative q row)
    const int c4  = idx & 15;             // 16B chunk within 64-kv tile row
    mreg[it] = *(const i32x4*)(Mb + (size_t)(q0 + row) * SEQ + k0 + c4 * 4);
  }
}

__global__ __launch_bounds__(256, 2) void attn_fwd(
    const float* __restrict__ Vg, const float* __restrict__ Kg,
    const float* __restrict__ Qg, const int* __restrict__ Mg,
    float* __restrict__ Og) {
  __shared__ short lds_k[KVBLK * KPAD];    // K tile, bf16 row-major [kv][d]
  __shared__ short lds_vt[DIM * VPAD];     // V tile transposed [d][kv]
  __shared__ short lds_p[4][16 * PPAD];    // per-wave P tile [q][kv]
  __shared__ int   lds_m[QBLK * MPAD];     // mask tile [q(block-rel)][kv]

  const int tid = threadIdx.x;
  const int w   = tid >> 6;
  const int l   = tid & 63;
  const int g   = l >> 4;
  const int lr  = l & 15;

  const int blk = blockIdx.x;
  const int b   = blk >> 5;
  const int q0  = (blk & 31) * QBLK;

  const float scale = 0.08838834764831845f;  // 1/sqrt(128)

  // ---- Q fragments (A-layout: row = lr, k = g*8 + kk*32 + j), pre-scaled
  bf16x8 qa[4];
  {
    const float* qbase = Qg + ((size_t)b * SEQ + (size_t)(q0 + w * 16 + lr)) * DIM + g * 8;
    #pragma unroll
    for (int kk = 0; kk < 4; ++kk) {
      const float4 x0 = *(const float4*)(qbase + kk * 32);
      const float4 x1 = *(const float4*)(qbase + kk * 32 + 4);
      bf16x8 f;
      f[0] = f2bf(x0.x * scale); f[1] = f2bf(x0.y * scale);
      f[2] = f2bf(x0.z * scale); f[3] = f2bf(x0.w * scale);
      f[4] = f2bf(x1.x * scale); f[5] = f2bf(x1.y * scale);
      f[6] = f2bf(x1.z * scale); f[7] = f2bf(x1.w * scale);
      qa[kk] = f;
    }
  }

  f32x4 acc[8];
  #pragma unroll
  for (int t = 0; t < 8; ++t) acc[t] = (f32x4){0.f, 0.f, 0.f, 0.f};
  float mrow[4] = {-1e30f, -1e30f, -1e30f, -1e30f};
  float lsum[4] = {0.f, 0.f, 0.f, 0.f};

  const float* Kb = Kg + (size_t)b * SEQ * DIM;
  const float* Vb = Vg + (size_t)b * SEQ * DIM;
  const int*   Mb = Mg + (size_t)b * SEQ * SEQ;

  // ---- prefetch registers
  float4 kreg[8];
  float  vreg[32];
  i32x4  mreg[4];

  issue_kv(Kb, Vb, 0, tid, kreg, vreg);
  issue_m(Mb, q0, 0, tid, mreg);

  for (int t = 0; t < NT; ++t) {
    const int k0 = t * KVBLK;
    __syncthreads();   // prev tile's LDS reads done

    // ---- write prefetched K tile to LDS (f32 regs -> bf16)
    #pragma unroll
    for (int it = 0; it < 8; ++it) {
      const int idx = tid + it * 256;
      const int row = idx >> 5;
      const int c4  = idx & 31;
      const float4 x = kreg[it];
      bf16x4 y;
      y[0] = f2bf(x.x); y[1] = f2bf(x.y); y[2] = f2bf(x.z); y[3] = f2bf(x.w);
      *(bf16x4*)&lds_k[row * KPAD + c4 * 4] = y;
    }
    // ---- write prefetched V tile (transposed) to LDS
    {
      const int d = tid & 127;
      #pragma unroll
      for (int st = 0; st < 8; ++st) {
        const int kv0 = ((tid >> 7) + 2 * st) * 4;
        bf16x4 y;
        y[0] = f2bf(vreg[st * 4 + 0]); y[1] = f2bf(vreg[st * 4 + 1]);
        y[2] = f2bf(vreg[st * 4 + 2]); y[3] = f2bf(vreg[st * 4 + 3]);
        *(bf16x4*)&lds_vt[d * VPAD + kv0] = y;
      }
    }
    // ---- write prefetched mask tile to LDS
    #pragma unroll
    for (int it = 0; it < 4; ++it) {
      const int idx = tid + it * 256;
      const int row = idx >> 4;
      const int c4  = idx & 15;
      *(i32x4*)&lds_m[row * MPAD + c4 * 4] = mreg[it];
    }
    __syncthreads();

    // ---- issue next tile's K/V/M loads: latency hides under compute (T14)
    if (t + 1 < NT) {
      issue_kv(Kb, Vb, k0 + KVBLK, tid, kreg, vreg);
      issue_m(Mb, q0, k0 + KVBLK, tid, mreg);
    }

    // ---- QK^T
    f32x4 s[4];
    #pragma unroll
    for (int sub = 0; sub < 4; ++sub) {
      f32x4 sv = (f32x4){0.f, 0.f, 0.f, 0.f};
      const int krow = sub * 16 + lr;
      #pragma unroll
      for (int kk = 0; kk < 4; ++kk) {
        bf16x8 kb = *(const bf16x8*)&lds_k[krow * KPAD + kk * 32 + g * 8];
        sv = __builtin_amdgcn_mfma_f32_16x16x32_bf16(qa[kk], kb, sv, 0, 0, 0);
      }
      s[sub] = sv;
    }

    // ---- apply mask from LDS (C-layout: row = w*16+4g+i, col = 16*sub+lr)
    #pragma unroll
    for (int sub = 0; sub < 4; ++sub) {
      #pragma unroll
      for (int i = 0; i < 4; ++i) {
        if (lds_m[(w * 16 + 4 * g + i) * MPAD + sub * 16 + lr] == MSENT)
          s[sub][i] = -1e30f;
      }
    }

    // ---- online softmax with defer-max (T13)
    float tmax[4];
    bool chg = false;
    #pragma unroll
    for (int i = 0; i < 4; ++i) {
      float tm = fmaxf(fmaxf(s[0][i], s[1][i]), fmaxf(s[2][i], s[3][i]));
      #pragma unroll
      for (int dlt = 1; dlt < 16; dlt <<= 1)
        tm = fmaxf(tm, __shfl_xor(tm, dlt, 16));
      tmax[i] = tm;
      chg = chg || (tm > mrow[i] + THR);
    }
    if (__any(chg)) {   // wave-uniform; skipped ~31/32 tiles after warm-up
      #pragma unroll
      for (int i = 0; i < 4; ++i) {
        const float mnew = fmaxf(mrow[i], tmax[i]);
        const float alpha = __builtin_amdgcn_exp2f((mrow[i] - mnew) * L2E);
        mrow[i] = mnew;
        lsum[i] *= alpha;
        #pragma unroll
        for (int t8 = 0; t8 < 8; ++t8) acc[t8][i] *= alpha;
      }
    }

    // ---- P = exp2((s - m)*L2E)  (bounded by 2^(THR*L2E) ~ 2900, bf16-safe)
    #pragma unroll
    for (int sub = 0; sub < 4; ++sub) {
      #pragma unroll
      for (int i = 0; i < 4; ++i) {
        const float p = __builtin_amdgcn_exp2f((s[sub][i] - mrow[i]) * L2E);
        lsum[i] += p;
        lds_p[w][(4 * g + i) * PPAD + sub * 16 + lr] = f2bf(p);
      }
    }

    // ---- PV
    bf16x8 pa[2];
    #pragma unroll
    for (int kk = 0; kk < 2; ++kk)
      pa[kk] = *(const bf16x8*)&lds_p[w][lr * PPAD + kk * 32 + g * 8];
    #pragma unroll
    for (int t8 = 0; t8 < 8; ++t8) {
      #pragma unroll
      for (int kk = 0; kk < 2; ++kk) {
        const int voff = (16 * t8 + lr) * VPAD + kk * 32 + g * 8;
        bf16x4 v0 = *(const bf16x4*)&lds_vt[voff];
        bf16x4 v1 = *(const bf16x4*)&lds_vt[voff + 4];
        bf16x8 vb = __builtin_shufflevector(v0, v1, 0, 1, 2, 3, 4, 5, 6, 7);
        acc[t8] = __builtin_amdgcn_mfma_f32_16x16x32_bf16(pa[kk], vb, acc[t8], 0, 0, 0);
      }
    }
  }

  // ---- finalize
  float rden[4];
  #pragma unroll
  for (int i = 0; i < 4; ++i) {
    float sm = lsum[i];
    #pragma unroll
    for (int dlt = 1; dlt < 16; dlt <<= 1) sm += __shfl_xor(sm, dlt, 16);
    rden[i] = 1.f / sm;
  }
  float* ob = Og + ((size_t)b * SEQ + (size_t)(q0 + w * 16)) * DIM;
  #pragma unroll
  for (int t8 = 0; t8 < 8; ++t8) {
    #pragma unroll
    for (int i = 0; i < 4; ++i)
      ob[(4 * g + i) * DIM + 16 * t8 + lr] = acc[t8][i] * rden[i];
  }
}

extern "C" void kernel_launch(void* const* d_in, const int* in_sizes, int n_in,
                              void* d_out, int out_size, void* d_ws, size_t ws_size,
                              hipStream_t stream) {
  (void)in_sizes; (void)n_in; (void)d_ws; (void)ws_size; (void)out_size;
  const float* Vg = (const float*)d_in[0];
  const float* Kg = (const float*)d_in[1];
  const float* Qg = (const float*)d_in[2];
  const int*   Mg = (const int*)d_in[3];
  float* Og = (float*)d_out;
  dim3 grid(BATCH * (SEQ / QBLK));
  attn_fwd<<<grid, 256, 0, stream>>>(Vg, Kg, Qg, Mg, Og);
}

// Round 5
// 118.375 us; speedup vs baseline: 2.5083x; 1.1392x over previous
//
#include <hip/hip_runtime.h>
#include <hip/hip_bf16.h>

#define BATCH 16
#define SEQ   2048
#define DIM   128
#define QBLK  64       // q rows per block (4 waves x 16)
#define KVBLK 64
#define NT    (SEQ / KVBLK)
#define PPAD  72       // lds_p row stride (elems)
#define L2E   1.4426950408889634f
#define THR   8.0f
#define MSENT -100

typedef __attribute__((ext_vector_type(8))) short bf16x8;
typedef __attribute__((ext_vector_type(4))) short bf16x4;
typedef __attribute__((ext_vector_type(4))) float f32x4;
typedef __attribute__((ext_vector_type(4))) unsigned u32x4;

__device__ __forceinline__ unsigned short f2bf(float f) {
  union { float f; unsigned u; } v; v.f = f;
  return (unsigned short)((v.u + 0x7FFFu + ((v.u >> 16) & 1u)) >> 16);  // RTNE
}
__device__ __forceinline__ unsigned packbf(float a, float b) {
  return ((unsigned)f2bf(b) << 16) | (unsigned)f2bf(a);
}

// ---------------- Pass 1a: K f32 -> bf16 (same layout) ----------------
__global__ __launch_bounds__(256) void cvt_k(const float* __restrict__ K,
                                             short* __restrict__ Kb) {
  const size_t i = ((size_t)blockIdx.x * 256 + threadIdx.x) * 8;
  f32x4 a = __builtin_nontemporal_load((const f32x4*)(K + i));
  f32x4 b = __builtin_nontemporal_load((const f32x4*)(K + i + 4));
  u32x4 o = { packbf(a[0], a[1]), packbf(a[2], a[3]),
              packbf(b[0], b[1]), packbf(b[2], b[3]) };
  *(u32x4*)(Kb + i) = o;
}

// ---------------- Pass 1b: V f32 [b][s][d] -> bf16 Vt [b][d][s] ----------------
__global__ __launch_bounds__(256) void cvt_vt(const float* __restrict__ V,
                                              short* __restrict__ Vt) {
  __shared__ unsigned t32[64][65];   // u32 = packed bf16 pair (d even, d odd)
  const int tid = threadIdx.x;
  const int b  = blockIdx.x >> 5;
  const int s0 = (blockIdx.x & 31) * 64;
  #pragma unroll
  for (int it = 0; it < 8; ++it) {
    const int idx = tid + it * 256;
    const int r = idx >> 5, c4 = idx & 31;
    f32x4 x = __builtin_nontemporal_load(
        (const f32x4*)(V + ((size_t)b * SEQ + s0 + r) * DIM + c4 * 4));
    t32[r][c4 * 2]     = packbf(x[0], x[1]);
    t32[r][c4 * 2 + 1] = packbf(x[2], x[3]);
  }
  __syncthreads();
  const int d = tid >> 1, sh = tid & 1;
  unsigned short outv[32];
  #pragma unroll
  for (int j = 0; j < 32; ++j) {
    const unsigned u = t32[sh * 32 + j][d >> 1];
    outv[j] = (d & 1) ? (unsigned short)(u >> 16) : (unsigned short)(u & 0xffff);
  }
  short* op = Vt + ((size_t)b * DIM + d) * SEQ + s0 + sh * 32;
  #pragma unroll
  for (int q = 0; q < 4; ++q) {
    bf16x8 y;
    #pragma unroll
    for (int j = 0; j < 8; ++j) y[j] = (short)outv[q * 8 + j];
    *(bf16x8*)(op + q * 8) = y;
  }
}

// ---------------- async 16B global->LDS ----------------
__device__ __forceinline__ void gload16(const void* g, void* l) {
  __builtin_amdgcn_global_load_lds(
      (const __attribute__((address_space(1))) unsigned*)g,
      (__attribute__((address_space(3))) unsigned*)l, 16, 0, 0);
}

// Stage K tile [64][128]bf16 + V tile [128][64]bf16 into LDS, swizzled:
// LDS linear dest; SOURCE address pre-swizzled by c ^= (row&7)<<4 (rule #21).
__device__ __forceinline__ void stage_kv(const char* __restrict__ Kb2,
                                         const char* __restrict__ Vtb2,
                                         int k0, int w, int l,
                                         short* kbuf, short* vbuf) {
  #pragma unroll
  for (int it = 0; it < 4; ++it) {
    const int ch = w * 4 + it;              // 1KB chunk 0..15
    const int r  = ch * 4 + (l >> 4);       // K row (kv) 0..63
    const int cs = ((l & 15) * 16) ^ ((r & 7) << 4);
    gload16(Kb2 + (size_t)(k0 + r) * 256 + cs, (char*)kbuf + ch * 1024);
  }
  #pragma unroll
  for (int it = 0; it < 4; ++it) {
    const int ch = w * 4 + it;
    const int d  = ch * 8 + (l >> 3);       // V row (d) 0..127
    const int cs = ((l & 7) * 16) ^ ((d & 7) << 4);
    gload16(Vtb2 + (size_t)d * (SEQ * 2) + k0 * 2 + cs, (char*)vbuf + ch * 1024);
  }
}

// ---------------- Pass 2: flash attention ----------------
__global__ __launch_bounds__(256, 2) void attn_fwd(
    const short* __restrict__ Kbf, const short* __restrict__ Vt,
    const float* __restrict__ Qg, const int* __restrict__ Mg,
    float* __restrict__ Og) {
  __shared__ short lds_k[2][KVBLK * DIM];   // 2 x 16KB, swizzled rows (256B)
  __shared__ short lds_v[2][DIM * KVBLK];   // 2 x 16KB, swizzled rows (128B)
  __shared__ short lds_p[4][16 * PPAD];     // per-wave P tile

  const int tid = threadIdx.x;
  const int w   = tid >> 6;
  const int l   = tid & 63;
  const int g   = l >> 4;
  const int lr  = l & 15;

  const int blk = blockIdx.x;
  const int b   = blk >> 5;
  const int q0  = (blk & 31) * QBLK;

  const float scale = 0.08838834764831845f;  // 1/sqrt(128)

  const char* Kb2  = (const char*)(Kbf + (size_t)b * SEQ * DIM);
  const char* Vtb2 = (const char*)(Vt  + (size_t)b * DIM * SEQ);
  const int*  Mb   = Mg + (size_t)b * SEQ * SEQ;
  const int* const Mrow[4] = {
    Mb + (size_t)(q0 + w * 16 + 4 * g + 0) * SEQ + lr,
    Mb + (size_t)(q0 + w * 16 + 4 * g + 1) * SEQ + lr,
    Mb + (size_t)(q0 + w * 16 + 4 * g + 2) * SEQ + lr,
    Mb + (size_t)(q0 + w * 16 + 4 * g + 3) * SEQ + lr };

  // ---- stage tile 0 (async, zero VGPR) + mask tile 0 prefetch
  stage_kv(Kb2, Vtb2, 0, w, l, lds_k[0], lds_v[0]);
  int mreg[16];
  #pragma unroll
  for (int sub = 0; sub < 4; ++sub)
    #pragma unroll
    for (int i = 0; i < 4; ++i)
      mreg[sub * 4 + i] = __builtin_nontemporal_load(Mrow[i] + sub * 16);

  // ---- Q fragments (A-layout: row = lr, k = g*8 + kk*32 + j), pre-scaled
  bf16x8 qa[4];
  {
    const float* qbase = Qg + ((size_t)b * SEQ + (size_t)(q0 + w * 16 + lr)) * DIM + g * 8;
    #pragma unroll
    for (int kk = 0; kk < 4; ++kk) {
      f32x4 x0 = *(const f32x4*)(qbase + kk * 32);
      f32x4 x1 = *(const f32x4*)(qbase + kk * 32 + 4);
      bf16x8 f;
      #pragma unroll
      for (int j = 0; j < 4; ++j) {
        f[j]     = (short)f2bf(x0[j] * scale);
        f[j + 4] = (short)f2bf(x1[j] * scale);
      }
      qa[kk] = f;
    }
  }

  f32x4 acc[8];
  #pragma unroll
  for (int t = 0; t < 8; ++t) acc[t] = (f32x4){0.f, 0.f, 0.f, 0.f};
  float mrow[4] = {-1e30f, -1e30f, -1e30f, -1e30f};
  float lsum[4] = {0.f, 0.f, 0.f, 0.f};

  __syncthreads();   // drains vmcnt(0): stage(0) + Q loads complete
  int cur = 0;

  for (int t = 0; t < NT; ++t) {
    const int k0 = t * KVBLK;
    // ---- issue next tile's staging NOW; latency hides under compute(t).
    // Safe: buffer cur^1 was last read in tile t-1, barrier'd since.
    if (t + 1 < NT)
      stage_kv(Kb2, Vtb2, k0 + KVBLK, w, l, lds_k[cur ^ 1], lds_v[cur ^ 1]);

    const char* kbuf = (const char*)lds_k[cur];
    const char* vbuf = (const char*)lds_v[cur];

    // ---- QK^T: swizzled ds_read_b128 (2-way max bank aliasing)
    f32x4 s[4];
    #pragma unroll
    for (int sub = 0; sub < 4; ++sub) {
      f32x4 sv = (f32x4){0.f, 0.f, 0.f, 0.f};
      const int krow = sub * 16 + lr;
      #pragma unroll
      for (int kk = 0; kk < 4; ++kk) {
        const int cb = (kk * 64 + g * 16) ^ ((krow & 7) << 4);
        bf16x8 kb = *(const bf16x8*)(kbuf + krow * 256 + cb);
        sv = __builtin_amdgcn_mfma_f32_16x16x32_bf16(qa[kk], kb, sv, 0, 0, 0);
      }
      s[sub] = sv;
    }

    // ---- apply prefetched mask (C-layout: row q=4g+i, col kv=16sub+lr)
    #pragma unroll
    for (int sub = 0; sub < 4; ++sub)
      #pragma unroll
      for (int i = 0; i < 4; ++i)
        if (mreg[sub * 4 + i] == MSENT) s[sub][i] = -1e30f;
    if (t + 1 < NT) {
      #pragma unroll
      for (int sub = 0; sub < 4; ++sub)
        #pragma unroll
        for (int i = 0; i < 4; ++i)
          mreg[sub * 4 + i] =
              __builtin_nontemporal_load(Mrow[i] + k0 + KVBLK + sub * 16);
    }

    // ---- online softmax with defer-max (T13)
    float tmax[4];
    bool chg = false;
    #pragma unroll
    for (int i = 0; i < 4; ++i) {
      float tm = fmaxf(fmaxf(s[0][i], s[1][i]), fmaxf(s[2][i], s[3][i]));
      #pragma unroll
      for (int dlt = 1; dlt < 16; dlt <<= 1)
        tm = fmaxf(tm, __shfl_xor(tm, dlt, 16));
      tmax[i] = tm;
      chg = chg || (tm > mrow[i] + THR);
    }
    if (__any(chg)) {   // wave-uniform; rare after warm-up
      #pragma unroll
      for (int i = 0; i < 4; ++i) {
        const float mnew = fmaxf(mrow[i], tmax[i]);
        const float alpha = __builtin_amdgcn_exp2f((mrow[i] - mnew) * L2E);
        mrow[i] = mnew;
        lsum[i] *= alpha;
        #pragma unroll
        for (int t8 = 0; t8 < 8; ++t8) acc[t8][i] *= alpha;
      }
    }

    // ---- P = exp2((s-m)*L2E), C->A layout via per-wave LDS
    #pragma unroll
    for (int sub = 0; sub < 4; ++sub)
      #pragma unroll
      for (int i = 0; i < 4; ++i) {
        const float p = __builtin_amdgcn_exp2f((s[sub][i] - mrow[i]) * L2E);
        lsum[i] += p;
        lds_p[w][(4 * g + i) * PPAD + sub * 16 + lr] = (short)f2bf(p);
      }

    // ---- PV: swizzled V reads (b128, balanced banks)
    bf16x8 pa[2];
    #pragma unroll
    for (int kk = 0; kk < 2; ++kk)
      pa[kk] = *(const bf16x8*)&lds_p[w][lr * PPAD + kk * 32 + g * 8];
    #pragma unroll
    for (int t8 = 0; t8 < 8; ++t8) {
      const int d = 16 * t8 + lr;
      #pragma unroll
      for (int kk = 0; kk < 2; ++kk) {
        const int cb = (kk * 64 + g * 16) ^ ((d & 7) << 4);
        bf16x8 vb = *(const bf16x8*)(vbuf + d * 128 + cb);
        acc[t8] = __builtin_amdgcn_mfma_f32_16x16x32_bf16(pa[kk], vb, acc[t8], 0, 0, 0);
      }
    }

    __syncthreads();   // vmcnt(0)+lgkmcnt(0) drain: stage(t+1) lands exactly here
    cur ^= 1;
  }

  // ---- finalize
  float rden[4];
  #pragma unroll
  for (int i = 0; i < 4; ++i) {
    float sm = lsum[i];
    #pragma unroll
    for (int dlt = 1; dlt < 16; dlt <<= 1) sm += __shfl_xor(sm, dlt, 16);
    rden[i] = 1.f / sm;
  }
  float* ob = Og + ((size_t)b * SEQ + (size_t)(q0 + w * 16)) * DIM;
  #pragma unroll
  for (int t8 = 0; t8 < 8; ++t8)
    #pragma unroll
    for (int i = 0; i < 4; ++i)
      ob[(4 * g + i) * DIM + 16 * t8 + lr] = acc[t8][i] * rden[i];
}

extern "C" void kernel_launch(void* const* d_in, const int* in_sizes, int n_in,
                              void* d_out, int out_size, void* d_ws, size_t ws_size,
                              hipStream_t stream) {
  (void)in_sizes; (void)n_in; (void)out_size; (void)ws_size;
  const float* Vg = (const float*)d_in[0];
  const float* Kg = (const float*)d_in[1];
  const float* Qg = (const float*)d_in[2];
  const int*   Mg = (const int*)d_in[3];
  float* Og = (float*)d_out;

  short* Kbf = (short*)d_ws;                       // 8 MB
  short* Vt  = Kbf + (size_t)BATCH * SEQ * DIM;    // 8 MB
  cvt_k<<<dim3(BATCH * SEQ * DIM / (8 * 256)), 256, 0, stream>>>(Kg, Kbf);
  cvt_vt<<<dim3(BATCH * (SEQ / 64)), 256, 0, stream>>>(Vg, Vt);
  attn_fwd<<<dim3(BATCH * (SEQ / QBLK)), 256, 0, stream>>>(Kbf, Vt, Qg, Mg, Og);
}

// Round 6
// 117.323 us; speedup vs baseline: 2.5308x; 1.0090x over previous
//
#include <hip/hip_runtime.h>
#include <hip/hip_bf16.h>

#define BATCH 16
#define SEQ   2048
#define DIM   128
#define QBLK  64       // q rows per block (4 waves x 16)
#define KVBLK 64
#define NT    (SEQ / KVBLK)
#define PPAD  72       // lds_p row stride (shorts)
#define L2E   1.4426950408889634f
#define THR   8.0f
#define MSENT -100

typedef __attribute__((ext_vector_type(8))) short bf16x8;
typedef __attribute__((ext_vector_type(4))) float f32x4;
typedef __attribute__((ext_vector_type(4))) int   i32x4;
typedef __attribute__((ext_vector_type(4))) unsigned u32x4;

__device__ __forceinline__ unsigned short f2bf(float f) {
  union { float f; unsigned u; } v; v.f = f;
  return (unsigned short)((v.u + 0x7FFFu + ((v.u >> 16) & 1u)) >> 16);  // RTNE
}
__device__ __forceinline__ unsigned packbf(float a, float b) {
  return ((unsigned)f2bf(b) << 16) | (unsigned)f2bf(a);
}

// ---------------- Pass 1a: K f32 -> bf16 (same layout) ----------------
__global__ __launch_bounds__(256) void cvt_k(const float* __restrict__ K,
                                             short* __restrict__ Kb) {
  const size_t i = ((size_t)blockIdx.x * 256 + threadIdx.x) * 8;
  f32x4 a = __builtin_nontemporal_load((const f32x4*)(K + i));
  f32x4 b = __builtin_nontemporal_load((const f32x4*)(K + i + 4));
  u32x4 o = { packbf(a[0], a[1]), packbf(a[2], a[3]),
              packbf(b[0], b[1]), packbf(b[2], b[3]) };
  *(u32x4*)(Kb + i) = o;
}

// ---------------- Pass 1b: V f32 [b][s][d] -> bf16 Vt [b][d][s] ----------------
__global__ __launch_bounds__(256) void cvt_vt(const float* __restrict__ V,
                                              short* __restrict__ Vt) {
  __shared__ unsigned t32[64][65];
  const int tid = threadIdx.x;
  const int b  = blockIdx.x >> 5;
  const int s0 = (blockIdx.x & 31) * 64;
  #pragma unroll
  for (int it = 0; it < 8; ++it) {
    const int idx = tid + it * 256;
    const int r = idx >> 5, c4 = idx & 31;
    f32x4 x = __builtin_nontemporal_load(
        (const f32x4*)(V + ((size_t)b * SEQ + s0 + r) * DIM + c4 * 4));
    t32[r][c4 * 2]     = packbf(x[0], x[1]);
    t32[r][c4 * 2 + 1] = packbf(x[2], x[3]);
  }
  __syncthreads();
  const int d = tid >> 1, sh = tid & 1;
  unsigned short outv[32];
  #pragma unroll
  for (int j = 0; j < 32; ++j) {
    const unsigned u = t32[sh * 32 + j][d >> 1];
    outv[j] = (d & 1) ? (unsigned short)(u >> 16) : (unsigned short)(u & 0xffff);
  }
  short* op = Vt + ((size_t)b * DIM + d) * SEQ + s0 + sh * 32;
  #pragma unroll
  for (int q = 0; q < 4; ++q) {
    bf16x8 y;
    #pragma unroll
    for (int j = 0; j < 8; ++j) y[j] = (short)outv[q * 8 + j];
    *(bf16x8*)(op + q * 8) = y;
  }
}

// ---------------- async 16B global->LDS ----------------
__device__ __forceinline__ void gload16(const void* g, void* l) {
  __builtin_amdgcn_global_load_lds(
      (const __attribute__((address_space(1))) unsigned*)g,
      (__attribute__((address_space(3))) unsigned*)l, 16, 0, 0);
}

// Stage K tile [64 rows x 256B] and V tile [64 d2-rows x 256B] into LDS.
// LDS dest is linear (wave-uniform base + lane*16); SOURCE address carries the
// inverse swizzle (rule #21).  K: slot ^= row&15.  V: paired-d rows, S ^= d2&15.
__device__ __forceinline__ void stage_kv(const char* __restrict__ Kb2,
                                         const char* __restrict__ Vtb2,
                                         int k0, int w, int l,
                                         void* kbuf, void* vbuf) {
  #pragma unroll
  for (int it = 0; it < 4; ++it) {
    const int ch = w * 4 + it;
    const int r  = ch * 4 + (l >> 4);            // K row (kv) 0..63
    const int sg = (l & 15) ^ (r & 15);          // global 16B slot
    gload16(Kb2 + (size_t)(k0 + r) * 256 + sg * 16, (char*)kbuf + ch * 1024);
  }
  #pragma unroll
  for (int it = 0; it < 4; ++it) {
    const int ch = w * 4 + it;
    const int d2 = ch * 4 + (l >> 4);            // paired-d row 0..63
    const int Su = (l & 15) ^ (d2 & 15);
    const int d  = 2 * d2 + (Su >> 3);           // V dim row 0..127
    const int m  = Su & 7;                       // kv 16B chunk 0..7
    gload16(Vtb2 + (size_t)d * (SEQ * 2) + k0 * 2 + m * 16,
            (char*)vbuf + ch * 1024);
  }
}

// ---------------- Pass 2: flash attention (swapped QK^T) ----------------
__global__ __launch_bounds__(256, 2) void attn_fwd(
    const short* __restrict__ Kbf, const short* __restrict__ Vt,
    const float* __restrict__ Qg, const int* __restrict__ Mg,
    float* __restrict__ Og) {
  __shared__ short lds_k[2][KVBLK * DIM];   // 2 x 16KB, 64 rows x 256B swizzled
  __shared__ short lds_v[2][DIM * KVBLK];   // 2 x 16KB, 64 d2-rows x 256B swizzled
  __shared__ short lds_p[4][16 * PPAD];     // per-wave P tile [q=lr][kv]

  const int tid = threadIdx.x;
  const int w   = tid >> 6;
  const int l   = tid & 63;
  const int g   = l >> 4;
  const int lr  = l & 15;

  const int blk = blockIdx.x;
  const int swz = (blk & 7) * 64 + (blk >> 3);   // XCD-chunked (512 % 8 == 0)
  const int b   = swz >> 5;
  const int q0  = (swz & 31) * QBLK;

  const float scale = 0.08838834764831845f;  // 1/sqrt(128)

  const char* Kb2  = (const char*)(Kbf + (size_t)b * SEQ * DIM);
  const char* Vtb2 = (const char*)(Vt  + (size_t)b * DIM * SEQ);
  const int*  Mr   = Mg + (size_t)b * SEQ * SEQ + (size_t)(q0 + w * 16 + lr) * SEQ;

  // ---- stage tile 0 (async, zero VGPR cost)
  stage_kv(Kb2, Vtb2, 0, w, l, lds_k[0], lds_v[0]);
  __builtin_amdgcn_sched_barrier(0);

  // ---- Q fragments (per-lane q = lr; used as B operand), pre-scaled
  bf16x8 qa[4];
  {
    const float* qbase = Qg + ((size_t)b * SEQ + (size_t)(q0 + w * 16 + lr)) * DIM + g * 8;
    #pragma unroll
    for (int kk = 0; kk < 4; ++kk) {
      f32x4 x0 = *(const f32x4*)(qbase + kk * 32);
      f32x4 x1 = *(const f32x4*)(qbase + kk * 32 + 4);
      bf16x8 f;
      #pragma unroll
      for (int j = 0; j < 4; ++j) {
        f[j]     = (short)f2bf(x0[j] * scale);
        f[j + 4] = (short)f2bf(x1[j] * scale);
      }
      qa[kk] = f;
    }
  }
  __builtin_amdgcn_sched_barrier(0);

  // ---- mask tile 0 prefetch: i32x4, 16B/lane (rows q=lr, cols 16sub+4g+i)
  i32x4 mreg[4];
  #pragma unroll
  for (int sub = 0; sub < 4; ++sub)
    mreg[sub] = __builtin_nontemporal_load((const i32x4*)(Mr + 16 * sub + 4 * g));

  f32x4 acc[8];
  #pragma unroll
  for (int t = 0; t < 8; ++t) acc[t] = (f32x4){0.f, 0.f, 0.f, 0.f};
  float mrow = -1e30f, lsum = 0.f;

  // counted drain: stage(0) done, mask(0) (4 newest) may stay in flight
  asm volatile("s_waitcnt vmcnt(4)" ::: "memory");
  __builtin_amdgcn_s_barrier();

  int cur = 0;
  for (int t = 0; t < NT; ++t) {
    const int k0 = t * KVBLK;
    if (t + 1 < NT)
      stage_kv(Kb2, Vtb2, k0 + KVBLK, w, l, lds_k[cur ^ 1], lds_v[cur ^ 1]);
    __builtin_amdgcn_sched_barrier(0);   // pin: stage loads precede all below

    const char* kbuf = (const char*)lds_k[cur];
    const char* vbuf = (const char*)lds_v[cur];

    // ---- QK^T swapped: s[sub] rows kv=16sub+4g+i, col q=lr
    f32x4 s[4];
    #pragma unroll
    for (int sub = 0; sub < 4; ++sub) s[sub] = (f32x4){0.f, 0.f, 0.f, 0.f};
    #pragma unroll
    for (int kk = 0; kk < 4; ++kk) {
      #pragma unroll
      for (int sub = 0; sub < 4; ++sub) {
        const int krow = sub * 16 + lr;
        const int cb = (64 * kk + 16 * g) ^ (lr << 4);   // slot ^= row&15 (=lr)
        bf16x8 kb = *(const bf16x8*)(kbuf + krow * 256 + cb);
        s[sub] = __builtin_amdgcn_mfma_f32_16x16x32_bf16(kb, qa[kk], s[sub], 0, 0, 0);
      }
    }

    // ---- apply prefetched mask: s[sub][i] ~ mask[q=lr][k0+16sub+4g+i]
    #pragma unroll
    for (int sub = 0; sub < 4; ++sub)
      #pragma unroll
      for (int i = 0; i < 4; ++i)
        if (mreg[sub][i] == MSENT) s[sub][i] = -1e30f;
    if (t + 1 < NT) {
      #pragma unroll
      for (int sub = 0; sub < 4; ++sub)
        mreg[sub] = __builtin_nontemporal_load(
            (const i32x4*)(Mr + k0 + KVBLK + 16 * sub + 4 * g));
    }

    // ---- online softmax, lane-local (q = lr), defer-max (T13)
    float tm = -1e30f;
    #pragma unroll
    for (int sub = 0; sub < 4; ++sub)
      #pragma unroll
      for (int i = 0; i < 4; ++i) tm = fmaxf(tm, s[sub][i]);
    tm = fmaxf(tm, __shfl_xor(tm, 16));
    tm = fmaxf(tm, __shfl_xor(tm, 32));
    if (__any(tm > mrow + THR)) {
      const float mnew = fmaxf(mrow, tm);
      const float al = __builtin_amdgcn_exp2f((mrow - mnew) * L2E);
      mrow = mnew; lsum *= al;
      float av[4];
      #pragma unroll
      for (int i = 0; i < 4; ++i) av[i] = __shfl(al, 4 * g + i);
      #pragma unroll
      for (int t8 = 0; t8 < 8; ++t8)
        #pragma unroll
        for (int i = 0; i < 4; ++i) acc[t8][i] *= av[i];
    }

    // ---- P = exp2((s-m)*L2E); write paired u32 to per-wave lds_p row q=lr
    {
      unsigned* prow = (unsigned*)&lds_p[w][lr * PPAD];
      #pragma unroll
      for (int sub = 0; sub < 4; ++sub) {
        const float p0 = __builtin_amdgcn_exp2f((s[sub][0] - mrow) * L2E);
        const float p1 = __builtin_amdgcn_exp2f((s[sub][1] - mrow) * L2E);
        const float p2 = __builtin_amdgcn_exp2f((s[sub][2] - mrow) * L2E);
        const float p3 = __builtin_amdgcn_exp2f((s[sub][3] - mrow) * L2E);
        lsum += (p0 + p1) + (p2 + p3);
        prow[8 * sub + 2 * g]     = packbf(p0, p1);
        prow[8 * sub + 2 * g + 1] = packbf(p2, p3);
      }
    }

    // ---- PV: A = P (rows q=lr), B = V (paired-row swizzled reads)
    bf16x8 pa[2];
    #pragma unroll
    for (int kk = 0; kk < 2; ++kk)
      pa[kk] = *(const bf16x8*)&lds_p[w][lr * PPAD + kk * 32 + g * 8];
    #pragma unroll
    for (int t8 = 0; t8 < 8; ++t8) {
      const int d2 = 8 * t8 + (lr >> 1);
      #pragma unroll
      for (int kk = 0; kk < 2; ++kk) {
        const int S = ((lr & 1) * 8 + 4 * kk + g) ^ (d2 & 15);
        bf16x8 vb = *(const bf16x8*)(vbuf + d2 * 256 + S * 16);
        acc[t8] = __builtin_amdgcn_mfma_f32_16x16x32_bf16(pa[kk], vb, acc[t8], 0, 0, 0);
      }
    }

    if (t + 1 < NT) {
      // counted: wait stage(t+1) (8), allow mask(t+1) (4 newest) in flight
      asm volatile("s_waitcnt vmcnt(4)" ::: "memory");
      __builtin_amdgcn_s_barrier();
    }
    cur ^= 1;
  }

  // ---- finalize: lane-local sum -> full row sum, normalize, store
  lsum += __shfl_xor(lsum, 16);
  lsum += __shfl_xor(lsum, 32);
  const float rden = 1.f / lsum;   // valid for q = lr (x4 dup)
  float rdv[4];
  #pragma unroll
  for (int i = 0; i < 4; ++i) rdv[i] = __shfl(rden, 4 * g + i);
  float* ob = Og + ((size_t)b * SEQ + (size_t)(q0 + w * 16)) * DIM;
  #pragma unroll
  for (int t8 = 0; t8 < 8; ++t8)
    #pragma unroll
    for (int i = 0; i < 4; ++i)
      ob[(4 * g + i) * DIM + 16 * t8 + lr] = acc[t8][i] * rdv[i];
}

extern "C" void kernel_launch(void* const* d_in, const int* in_sizes, int n_in,
                              void* d_out, int out_size, void* d_ws, size_t ws_size,
                              hipStream_t stream) {
  (void)in_sizes; (void)n_in; (void)out_size; (void)ws_size;
  const float* Vg = (const float*)d_in[0];
  const float* Kg = (const float*)d_in[1];
  const float* Qg = (const float*)d_in[2];
  const int*   Mg = (const int*)d_in[3];
  float* Og = (float*)d_out;

  short* Kbf = (short*)d_ws;                       // 8 MB
  short* Vt  = Kbf + (size_t)BATCH * SEQ * DIM;    // 8 MB
  cvt_k<<<dim3(BATCH * SEQ * DIM / (8 * 256)), 256, 0, stream>>>(Kg, Kbf);
  cvt_vt<<<dim3(BATCH * (SEQ / 64)), 256, 0, stream>>>(Vg, Vt);
  attn_fwd<<<dim3(BATCH * (SEQ / QBLK)), 256, 0, stream>>>(Kbf, Vt, Qg, Mg, Og);
}